// Round 2
// baseline (501.277 us; speedup 1.0000x reference)
//
#include <hip/hip_runtime.h>
#include <stdint.h>

#define N_NODES 50000
#define N_EDGES 800000

// ---------------- CSR build ----------------

__global__ void count_kernel(const int* __restrict__ dst,
                             int* __restrict__ cnt, int e) {
    int i = blockIdx.x * blockDim.x + threadIdx.x;
    if (i < e) atomicAdd(&cnt[dst[i]], 1);
}

__global__ void dinv_kernel(const int* __restrict__ cnt,
                            float* __restrict__ dinv, int n) {
    int i = blockIdx.x * blockDim.x + threadIdx.x;
    if (i < n) dinv[i] = rsqrtf((float)(cnt[i] + 1));  // +1 self-loop; always >0
}

// single-block exclusive scan over n=50000 counts -> rowptr[n+1]
__global__ void scan_kernel(const int* __restrict__ cnt,
                            int* __restrict__ rowptr, int n) {
    __shared__ int part[1024];
    int tid = threadIdx.x;
    int chunk = (n + 1023) >> 10;           // 49
    int b = tid * chunk;
    int e = min(b + chunk, n);
    int s = 0;
    for (int i = b; i < e; ++i) s += cnt[i];
    part[tid] = s;
    __syncthreads();
    // Hillis-Steele inclusive scan of per-thread partials
    for (int off = 1; off < 1024; off <<= 1) {
        int v = (tid >= off) ? part[tid - off] : 0;
        __syncthreads();
        part[tid] += v;
        __syncthreads();
    }
    int run = (tid == 0) ? 0 : part[tid - 1];   // exclusive base
    for (int i = b; i < e; ++i) { rowptr[i] = run; run += cnt[i]; }
    if (e == n) rowptr[n] = run;  // all threads past the end write the same total
}

__global__ void fill_kernel(const int* __restrict__ src,
                            const int* __restrict__ dst,
                            const int* __restrict__ rowptr,
                            int* __restrict__ fill,
                            const float* __restrict__ dinv,
                            int* __restrict__ col, float* __restrict__ nrm, int e) {
    int i = blockIdx.x * blockDim.x + threadIdx.x;
    if (i >= e) return;
    int s = src[i], d = dst[i];
    int pos = rowptr[d] + atomicAdd(&fill[d], 1);
    col[pos] = s;
    nrm[pos] = dinv[s] * dinv[d];
}

// ---------------- dense GEMM: out[n,C] = in[n,128] @ W[128,C] (+bias) ----------------
// C columns x G row-groups per block (C*G threads). Each thread: R rows, 1 col.
// W staged in LDS (lanes read consecutive cols -> 2-way bank alias = free).
// x rows read via wave-uniform addresses -> compiler emits scalar s_loads.

template <int C, int G, int R>
__global__ __launch_bounds__(C * G) void gemm_kernel(
        const float* __restrict__ in, const float* __restrict__ W,
        const float* __restrict__ bias, float* __restrict__ out, int n) {
    __shared__ float Wl[128 * C];
    int tid = threadIdx.x;
    for (int i = tid; i < 128 * C; i += C * G) Wl[i] = W[i];
    __syncthreads();
    int col = tid % C;
    int grp = __builtin_amdgcn_readfirstlane(tid / C);  // wave-uniform
    int row0 = blockIdx.x * (G * R) + grp * R;

    float acc[R];
#pragma unroll
    for (int r = 0; r < R; ++r) acc[r] = 0.f;

    const float* xp[R];
#pragma unroll
    for (int r = 0; r < R; ++r) {
        int rr = row0 + r;
        if (rr > n - 1) rr = n - 1;       // clamp (loads safe; stores guarded)
        xp[r] = in + (size_t)rr * 128;
    }

#pragma unroll 8
    for (int k = 0; k < 128; ++k) {
        float w = Wl[k * C + col];
#pragma unroll
        for (int r = 0; r < R; ++r) acc[r] = fmaf(xp[r][k], w, acc[r]);
    }

    float bv = bias ? bias[col] : 0.f;
#pragma unroll
    for (int r = 0; r < R; ++r) {
        int rr = row0 + r;
        if (rr < n) out[(size_t)rr * C + col] = acc[r] + bv;
    }
}

// ---------------- aggregation: out[d] = sum_e nrm[e]*t[col[e]] + dinv[d]^2*t[d] + b, relu ----------------
// one wave per dst node, float2 per lane (64 lanes x 2 = 128 features)

__global__ __launch_bounds__(256) void agg_kernel(
        const float* __restrict__ t, const int* __restrict__ rowptr,
        const int* __restrict__ col, const float* __restrict__ nrm,
        const float* __restrict__ dinv, const float* __restrict__ bias,
        float* __restrict__ out, int n, int relu) {
    int wid = __builtin_amdgcn_readfirstlane((int)blockIdx.x * 4 + ((int)threadIdx.x >> 6));
    int lane = threadIdx.x & 63;
    if (wid >= n) return;
    int beg = rowptr[wid], end = rowptr[wid + 1];
    float di = dinv[wid];
    const float2* tp = (const float2*)t;
    float2 sv = tp[(size_t)wid * 64 + lane];   // self-loop term
    float w0 = di * di;
    float ax = sv.x * w0, ay = sv.y * w0;
    for (int e = beg; e < end; ++e) {
        int s = col[e];       // wave-uniform -> scalar load
        float w = nrm[e];
        float2 v = tp[(size_t)s * 64 + lane];
        ax = fmaf(v.x, w, ax);
        ay = fmaf(v.y, w, ay);
    }
    float2 b = ((const float2*)bias)[lane];
    ax += b.x; ay += b.y;
    if (relu) { ax = fmaxf(ax, 0.f); ay = fmaxf(ay, 0.f); }
    float2 o; o.x = ax; o.y = ay;
    ((float2*)out)[(size_t)wid * 64 + lane] = o;
}

// ---------------- launch ----------------

extern "C" void kernel_launch(void* const* d_in, const int* in_sizes, int n_in,
                              void* d_out, int out_size, void* d_ws, size_t ws_size,
                              hipStream_t stream) {
    const float* x    = (const float*)d_in[0];
    const int*   ei   = (const int*)d_in[1];   // int64 in ref -> int32 on device
    const float* W1   = (const float*)d_in[2];
    const float* b1   = (const float*)d_in[3];
    const float* W2   = (const float*)d_in[4];
    const float* b2   = (const float*)d_in[5];
    const float* Wc   = (const float*)d_in[6];
    const float* bc   = (const float*)d_in[7];
    float*       out  = (float*)d_out;

    const int n = N_NODES, e = N_EDGES;
    const int* srcp = ei;        // edge_index[0]
    const int* dstp = ei + e;    // edge_index[1]

    char* ws = (char*)d_ws;
    size_t off = 0;
    auto alloc = [&](size_t bytes) {
        void* p = ws + off;
        off += (bytes + 255) & ~(size_t)255;
        return p;
    };
    int*   cnt    = (int*)  alloc((size_t)n * 4);
    int*   rowptr = (int*)  alloc((size_t)(n + 1) * 4);
    int*   fillc  = (int*)  alloc((size_t)n * 4);
    float* dinv   = (float*)alloc((size_t)n * 4);
    int*   col    = (int*)  alloc((size_t)e * 4);
    float* nrm    = (float*)alloc((size_t)e * 4);
    float* bufT   = (float*)alloc((size_t)n * 128 * 4);
    float* bufH   = (float*)alloc((size_t)n * 128 * 4);
    // total ~58.5 MB of workspace

    hipMemsetAsync(cnt,   0, (size_t)n * 4, stream);
    hipMemsetAsync(fillc, 0, (size_t)n * 4, stream);

    count_kernel<<<(e + 255) / 256, 256, 0, stream>>>(dstp, cnt, e);
    dinv_kernel<<<(n + 255) / 256, 256, 0, stream>>>(cnt, dinv, n);
    scan_kernel<<<1, 1024, 0, stream>>>(cnt, rowptr, n);
    fill_kernel<<<(e + 255) / 256, 256, 0, stream>>>(srcp, dstp, rowptr, fillc,
                                                     dinv, col, nrm, e);

    // conv1: t = x @ W1 ; h = relu(agg(t) + b1)
    gemm_kernel<128, 2, 8><<<n / 16, 256, 0, stream>>>(x, W1, nullptr, bufT, n);
    agg_kernel<<<n / 4, 256, 0, stream>>>(bufT, rowptr, col, nrm, dinv, b1, bufH, n, 1);
    // conv2
    gemm_kernel<128, 2, 8><<<n / 16, 256, 0, stream>>>(bufH, W2, nullptr, bufT, n);
    agg_kernel<<<n / 4, 256, 0, stream>>>(bufT, rowptr, col, nrm, dinv, b2, bufH, n, 1);
    // classifier: out = h @ Wc + bc
    gemm_kernel<64, 4, 8><<<(n + 31) / 32, 256, 0, stream>>>(bufH, Wc, bc, out, n);
}

// Round 3
// 377.013 us; speedup vs baseline: 1.3296x; 1.3296x over previous
//
#include <hip/hip_runtime.h>
#include <stdint.h>

#define N_NODES 50000
#define N_EDGES 800000

// ---------------- CSR build ----------------

__global__ void count_kernel(const int* __restrict__ dst,
                             int* __restrict__ cnt, int e) {
    int i = blockIdx.x * blockDim.x + threadIdx.x;
    if (i < e) atomicAdd(&cnt[dst[i]], 1);
}

__global__ void dinv_kernel(const int* __restrict__ cnt,
                            float* __restrict__ dinv, int n) {
    int i = blockIdx.x * blockDim.x + threadIdx.x;
    if (i < n) dinv[i] = rsqrtf((float)(cnt[i] + 1));  // +1 self-loop; always >0
}

// single-block exclusive scan over n=50000 counts -> rowptr[n+1]
__global__ void scan_kernel(const int* __restrict__ cnt,
                            int* __restrict__ rowptr, int n) {
    __shared__ int part[1024];
    int tid = threadIdx.x;
    int chunk = (n + 1023) >> 10;
    int b = tid * chunk;
    int e = min(b + chunk, n);
    int s = 0;
    for (int i = b; i < e; ++i) s += cnt[i];
    part[tid] = s;
    __syncthreads();
    for (int off = 1; off < 1024; off <<= 1) {
        int v = (tid >= off) ? part[tid - off] : 0;
        __syncthreads();
        part[tid] += v;
        __syncthreads();
    }
    int run = (tid == 0) ? 0 : part[tid - 1];
    for (int i = b; i < e; ++i) { rowptr[i] = run; run += cnt[i]; }
    if (e == n) rowptr[n] = run;
}

__global__ void fill_kernel(const int* __restrict__ src,
                            const int* __restrict__ dst,
                            const int* __restrict__ rowptr,
                            int* __restrict__ fill,
                            const float* __restrict__ dinv,
                            int* __restrict__ col, float* __restrict__ nrm, int e) {
    int i = blockIdx.x * blockDim.x + threadIdx.x;
    if (i >= e) return;
    int s = src[i], d = dst[i];
    int pos = rowptr[d] + atomicAdd(&fill[d], 1);
    col[pos] = s;
    nrm[pos] = dinv[s] * dinv[d];
}

// ---------------- tiled GEMM: out[n,C] = A[n,128] @ W[128,C] (+bias) ----------------
// Block: BM rows x C cols, 256 threads, thread tile RT x CT (CT=8).
// x tile transposed in LDS (PAD=BM+4 keeps float4 alignment, spreads banks);
// W chunk staged linearly. Register prefetch of next x chunk.

template <int C, int BM, int RT, int CT>
__global__ __launch_bounds__(256, 4) void gemm_kernel(
        const float* __restrict__ A, const float* __restrict__ W,
        const float* __restrict__ bias, float* __restrict__ out, int n) {
    constexpr int KC = 32;
    constexpr int NCOLT = C / CT;
    constexpr int NROWT = BM / RT;
    static_assert(NCOLT * NROWT == 256, "bad tile");
    constexpr int PAD = BM + 4;
    constexpr int K4 = KC / 4;                  // 8 float4 per row per chunk
    constexpr int XLOADS = (BM * K4) / 256;     // 4
    constexpr int WLOADS = (KC * C) / 1024;     // 4 (C=128) / 2 (C=64)
    constexpr int NT = 128 / KC;                // 4 chunks

    __shared__ float xT[KC * PAD];
    __shared__ float Wl[KC * C];

    const int tid = threadIdx.x;
    const int colt = tid % NCOLT;
    const int rowt = tid / NCOLT;
    const int row0 = blockIdx.x * BM;

    float acc[RT][CT];
#pragma unroll
    for (int r = 0; r < RT; ++r)
#pragma unroll
        for (int c = 0; c < CT; ++c) acc[r][c] = 0.f;

    int xk4[XLOADS], xrow[XLOADS];
    const float* aptr[XLOADS];
#pragma unroll
    for (int i = 0; i < XLOADS; ++i) {
        int flat = tid + i * 256;
        xk4[i] = flat % K4;
        xrow[i] = flat / K4;
        int rg = row0 + xrow[i];
        if (rg > n - 1) rg = n - 1;             // clamp loads; stores guarded
        aptr[i] = A + (size_t)rg * 128 + xk4[i] * 4;
    }
    float4 xr[XLOADS];
#pragma unroll
    for (int i = 0; i < XLOADS; ++i) xr[i] = *(const float4*)aptr[i];

    for (int t = 0; t < NT; ++t) {
        // stage W chunk t (linear, coalesced)
#pragma unroll
        for (int i = 0; i < WLOADS; ++i) {
            int f4 = tid + i * 256;
            *(float4*)&Wl[f4 * 4] = *(const float4*)&W[t * KC * C + f4 * 4];
        }
        // write x chunk transposed: xT[k][row]
#pragma unroll
        for (int i = 0; i < XLOADS; ++i) {
            xT[(xk4[i] * 4 + 0) * PAD + xrow[i]] = xr[i].x;
            xT[(xk4[i] * 4 + 1) * PAD + xrow[i]] = xr[i].y;
            xT[(xk4[i] * 4 + 2) * PAD + xrow[i]] = xr[i].z;
            xT[(xk4[i] * 4 + 3) * PAD + xrow[i]] = xr[i].w;
        }
        // prefetch next x chunk into regs (overlaps with barrier+compute issue)
        if (t < NT - 1) {
#pragma unroll
            for (int i = 0; i < XLOADS; ++i)
                xr[i] = *(const float4*)(aptr[i] + (t + 1) * KC);
        }
        __syncthreads();

#pragma unroll 2
        for (int kk = 0; kk < KC; ++kk) {
            float xv[RT], wv[CT];
            {
                const float* xb = &xT[kk * PAD + rowt * RT];
                float4 a = *(const float4*)xb;
                xv[0] = a.x; xv[1] = a.y; xv[2] = a.z; xv[3] = a.w;
                if constexpr (RT == 8) {
                    float4 b = *(const float4*)(xb + 4);
                    xv[4] = b.x; xv[5] = b.y; xv[6] = b.z; xv[7] = b.w;
                }
            }
            {
                const float* wb = &Wl[kk * C + colt * CT];
                float4 a = *(const float4*)wb;
                float4 b = *(const float4*)(wb + 4);
                wv[0] = a.x; wv[1] = a.y; wv[2] = a.z; wv[3] = a.w;
                wv[4] = b.x; wv[5] = b.y; wv[6] = b.z; wv[7] = b.w;
            }
#pragma unroll
            for (int r = 0; r < RT; ++r)
#pragma unroll
                for (int c = 0; c < CT; ++c)
                    acc[r][c] = fmaf(xv[r], wv[c], acc[r][c]);
        }
        __syncthreads();
    }

    float bv[CT];
#pragma unroll
    for (int c = 0; c < CT; ++c) bv[c] = bias ? bias[colt * CT + c] : 0.f;
#pragma unroll
    for (int r = 0; r < RT; ++r) {
        int rg = row0 + rowt * RT + r;
        if (rg < n) {
            float4 o0, o1;
            o0.x = acc[r][0] + bv[0]; o0.y = acc[r][1] + bv[1];
            o0.z = acc[r][2] + bv[2]; o0.w = acc[r][3] + bv[3];
            o1.x = acc[r][4] + bv[4]; o1.y = acc[r][5] + bv[5];
            o1.z = acc[r][6] + bv[6]; o1.w = acc[r][7] + bv[7];
            float* op = &out[(size_t)rg * C + colt * CT];
            *(float4*)op = o0;
            *(float4*)(op + 4) = o1;
        }
    }
}

// ---------------- aggregation: out[d] = sum_e nrm[e]*t[col[e]] + dinv[d]^2*t[d] + b, relu ----------------

__global__ __launch_bounds__(256) void agg_kernel(
        const float* __restrict__ t, const int* __restrict__ rowptr,
        const int* __restrict__ col, const float* __restrict__ nrm,
        const float* __restrict__ dinv, const float* __restrict__ bias,
        float* __restrict__ out, int n, int relu) {
    int wid = __builtin_amdgcn_readfirstlane((int)blockIdx.x * 4 + ((int)threadIdx.x >> 6));
    int lane = threadIdx.x & 63;
    if (wid >= n) return;
    int beg = rowptr[wid], end = rowptr[wid + 1];
    float di = dinv[wid];
    const float2* tp = (const float2*)t;
    float2 sv = tp[(size_t)wid * 64 + lane];
    float w0 = di * di;
    float ax = sv.x * w0, ay = sv.y * w0;
    for (int e = beg; e < end; ++e) {
        int s = col[e];
        float w = nrm[e];
        float2 v = tp[(size_t)s * 64 + lane];
        ax = fmaf(v.x, w, ax);
        ay = fmaf(v.y, w, ay);
    }
    float2 b = ((const float2*)bias)[lane];
    ax += b.x; ay += b.y;
    if (relu) { ax = fmaxf(ax, 0.f); ay = fmaxf(ay, 0.f); }
    float2 o; o.x = ax; o.y = ay;
    ((float2*)out)[(size_t)wid * 64 + lane] = o;
}

// ---------------- launch ----------------

extern "C" void kernel_launch(void* const* d_in, const int* in_sizes, int n_in,
                              void* d_out, int out_size, void* d_ws, size_t ws_size,
                              hipStream_t stream) {
    const float* x  = (const float*)d_in[0];
    const int*   ei = (const int*)d_in[1];   // int64 in ref -> int32 on device
    const float* W1 = (const float*)d_in[2];
    const float* b1 = (const float*)d_in[3];
    const float* W2 = (const float*)d_in[4];
    const float* b2 = (const float*)d_in[5];
    const float* Wc = (const float*)d_in[6];
    const float* bc = (const float*)d_in[7];
    float*       out = (float*)d_out;

    const int n = N_NODES, e = N_EDGES;
    const int* srcp = ei;
    const int* dstp = ei + e;

    char* ws = (char*)d_ws;
    size_t off = 0;
    auto alloc = [&](size_t bytes) {
        void* p = ws + off;
        off += (bytes + 255) & ~(size_t)255;
        return p;
    };
    int*   cnt    = (int*)  alloc((size_t)n * 4);
    int*   rowptr = (int*)  alloc((size_t)(n + 1) * 4);
    int*   fillc  = (int*)  alloc((size_t)n * 4);
    float* dinv   = (float*)alloc((size_t)n * 4);
    int*   col    = (int*)  alloc((size_t)e * 4);
    float* nrm    = (float*)alloc((size_t)e * 4);
    float* bufT   = (float*)alloc((size_t)n * 128 * 4);
    float* bufH   = (float*)alloc((size_t)n * 128 * 4);

    hipMemsetAsync(cnt,   0, (size_t)n * 4, stream);
    hipMemsetAsync(fillc, 0, (size_t)n * 4, stream);

    count_kernel<<<(e + 255) / 256, 256, 0, stream>>>(dstp, cnt, e);
    dinv_kernel<<<(n + 255) / 256, 256, 0, stream>>>(cnt, dinv, n);
    scan_kernel<<<1, 1024, 0, stream>>>(cnt, rowptr, n);
    fill_kernel<<<(e + 255) / 256, 256, 0, stream>>>(srcp, dstp, rowptr, fillc,
                                                     dinv, col, nrm, e);

    const int gb = (n + 127) / 128;  // 391 blocks

    // conv1: t = x @ W1 ; h = relu(agg(t) + b1)
    gemm_kernel<128, 128, 8, 8><<<gb, 256, 0, stream>>>(x, W1, nullptr, bufT, n);
    agg_kernel<<<(n + 3) / 4, 256, 0, stream>>>(bufT, rowptr, col, nrm, dinv, b1, bufH, n, 1);
    // conv2
    gemm_kernel<128, 128, 8, 8><<<gb, 256, 0, stream>>>(bufH, W2, nullptr, bufT, n);
    agg_kernel<<<(n + 3) / 4, 256, 0, stream>>>(bufT, rowptr, col, nrm, dinv, b2, bufH, n, 1);
    // classifier: out = h @ Wc + bc
    gemm_kernel<64, 128, 4, 8><<<gb, 256, 0, stream>>>(bufH, Wc, bc, out, n);
}

// Round 4
// 305.306 us; speedup vs baseline: 1.6419x; 1.2349x over previous
//
#include <hip/hip_runtime.h>
#include <stdint.h>

#define N_NODES 50000
#define N_EDGES 800000
#define NB_SCAN ((N_NODES + 255) / 256)   // 196 blocks

// ---------------- CSR build ----------------

__global__ void count_kernel(const int* __restrict__ dst,
                             int* __restrict__ cnt, int e) {
    int i = blockIdx.x * blockDim.x + threadIdx.x;
    if (i < e) atomicAdd(&cnt[dst[i]], 1);
}

// phase 1: per-block inclusive scan of cnt + per-block totals; also dinv
__global__ __launch_bounds__(256) void block_scan_kernel(
        const int* __restrict__ cnt, int* __restrict__ scanT,
        int* __restrict__ bsum, float* __restrict__ dinv, int n) {
    __shared__ int sh[256];
    int t = threadIdx.x;
    int i = blockIdx.x * 256 + t;
    int v = (i < n) ? cnt[i] : 0;
    if (i < n) dinv[i] = rsqrtf((float)(v + 1));  // +1 self-loop
    sh[t] = v;
    __syncthreads();
    for (int off = 1; off < 256; off <<= 1) {
        int u = (t >= off) ? sh[t - off] : 0;
        __syncthreads();
        sh[t] += u;
        __syncthreads();
    }
    if (i < n) scanT[i] = sh[t];           // inclusive within block
    if (t == 255) bsum[blockIdx.x] = sh[255];
}

// phase 2: exclusive scan of block sums (nb <= 256)
__global__ __launch_bounds__(256) void bsum_scan_kernel(
        const int* __restrict__ bsum, int* __restrict__ boff, int nb) {
    __shared__ int sh[256];
    int t = threadIdx.x;
    sh[t] = (t < nb) ? bsum[t] : 0;
    __syncthreads();
    for (int off = 1; off < 256; off <<= 1) {
        int u = (t >= off) ? sh[t - off] : 0;
        __syncthreads();
        sh[t] += u;
        __syncthreads();
    }
    if (t < nb) boff[t] = (t == 0) ? 0 : sh[t - 1];
}

// phase 3: rowptr[i+1] = scanT[i] + boff[block]; rowptr[0] = 0
__global__ __launch_bounds__(256) void rowptr_kernel(
        const int* __restrict__ scanT, const int* __restrict__ boff,
        int* __restrict__ rowptr, int n) {
    int i = blockIdx.x * 256 + threadIdx.x;
    if (i < n) {
        rowptr[i + 1] = scanT[i] + boff[blockIdx.x];
        if (i == 0) rowptr[0] = 0;
    }
}

__global__ void fill_kernel(const int* __restrict__ src,
                            const int* __restrict__ dst,
                            const int* __restrict__ rowptr,
                            int* __restrict__ fill,
                            const float* __restrict__ dinv,
                            int* __restrict__ col, float* __restrict__ nrm, int e) {
    int i = blockIdx.x * blockDim.x + threadIdx.x;
    if (i >= e) return;
    int s = src[i], d = dst[i];
    int pos = rowptr[d] + atomicAdd(&fill[d], 1);
    col[pos] = s;
    nrm[pos] = dinv[s] * dinv[d];
}

// ---------------- tiled GEMM: out[n,C] = A[n,128] @ W[128,C] (+bias) ----------------

template <int C, int BM, int RT, int CT>
__global__ __launch_bounds__(256, 4) void gemm_kernel(
        const float* __restrict__ A, const float* __restrict__ W,
        const float* __restrict__ bias, float* __restrict__ out, int n) {
    constexpr int KC = 32;
    constexpr int NCOLT = C / CT;
    constexpr int NROWT = BM / RT;
    static_assert(NCOLT * NROWT == 256, "bad tile");
    constexpr int PAD = BM + 4;
    constexpr int K4 = KC / 4;
    constexpr int XLOADS = (BM * K4) / 256;
    constexpr int WLOADS = (KC * C) / 1024;
    constexpr int NT = 128 / KC;

    __shared__ float xT[KC * PAD];
    __shared__ float Wl[KC * C];

    const int tid = threadIdx.x;
    const int colt = tid % NCOLT;
    const int rowt = tid / NCOLT;
    const int row0 = blockIdx.x * BM;

    float acc[RT][CT];
#pragma unroll
    for (int r = 0; r < RT; ++r)
#pragma unroll
        for (int c = 0; c < CT; ++c) acc[r][c] = 0.f;

    int xk4[XLOADS], xrow[XLOADS];
    const float* aptr[XLOADS];
#pragma unroll
    for (int i = 0; i < XLOADS; ++i) {
        int flat = tid + i * 256;
        xk4[i] = flat % K4;
        xrow[i] = flat / K4;
        int rg = row0 + xrow[i];
        if (rg > n - 1) rg = n - 1;
        aptr[i] = A + (size_t)rg * 128 + xk4[i] * 4;
    }
    float4 xr[XLOADS];
#pragma unroll
    for (int i = 0; i < XLOADS; ++i) xr[i] = *(const float4*)aptr[i];

    for (int t = 0; t < NT; ++t) {
#pragma unroll
        for (int i = 0; i < WLOADS; ++i) {
            int f4 = tid + i * 256;
            *(float4*)&Wl[f4 * 4] = *(const float4*)&W[t * KC * C + f4 * 4];
        }
#pragma unroll
        for (int i = 0; i < XLOADS; ++i) {
            xT[(xk4[i] * 4 + 0) * PAD + xrow[i]] = xr[i].x;
            xT[(xk4[i] * 4 + 1) * PAD + xrow[i]] = xr[i].y;
            xT[(xk4[i] * 4 + 2) * PAD + xrow[i]] = xr[i].z;
            xT[(xk4[i] * 4 + 3) * PAD + xrow[i]] = xr[i].w;
        }
        if (t < NT - 1) {
#pragma unroll
            for (int i = 0; i < XLOADS; ++i)
                xr[i] = *(const float4*)(aptr[i] + (t + 1) * KC);
        }
        __syncthreads();

#pragma unroll 2
        for (int kk = 0; kk < KC; ++kk) {
            float xv[RT], wv[CT];
            {
                const float* xb = &xT[kk * PAD + rowt * RT];
                float4 a = *(const float4*)xb;
                xv[0] = a.x; xv[1] = a.y; xv[2] = a.z; xv[3] = a.w;
                if constexpr (RT == 8) {
                    float4 b = *(const float4*)(xb + 4);
                    xv[4] = b.x; xv[5] = b.y; xv[6] = b.z; xv[7] = b.w;
                }
            }
            {
                const float* wb = &Wl[kk * C + colt * CT];
                float4 a = *(const float4*)wb;
                float4 b = *(const float4*)(wb + 4);
                wv[0] = a.x; wv[1] = a.y; wv[2] = a.z; wv[3] = a.w;
                wv[4] = b.x; wv[5] = b.y; wv[6] = b.z; wv[7] = b.w;
            }
#pragma unroll
            for (int r = 0; r < RT; ++r)
#pragma unroll
                for (int c = 0; c < CT; ++c)
                    acc[r][c] = fmaf(xv[r], wv[c], acc[r][c]);
        }
        __syncthreads();
    }

    float bv[CT];
#pragma unroll
    for (int c = 0; c < CT; ++c) bv[c] = bias ? bias[colt * CT + c] : 0.f;
#pragma unroll
    for (int r = 0; r < RT; ++r) {
        int rg = row0 + rowt * RT + r;
        if (rg < n) {
            float4 o0, o1;
            o0.x = acc[r][0] + bv[0]; o0.y = acc[r][1] + bv[1];
            o0.z = acc[r][2] + bv[2]; o0.w = acc[r][3] + bv[3];
            o1.x = acc[r][4] + bv[4]; o1.y = acc[r][5] + bv[5];
            o1.z = acc[r][6] + bv[6]; o1.w = acc[r][7] + bv[7];
            float* op = &out[(size_t)rg * C + colt * CT];
            *(float4*)op = o0;
            *(float4*)(op + 4) = o1;
        }
    }
}

// ---------------- aggregation ----------------

__global__ __launch_bounds__(256) void agg_kernel(
        const float* __restrict__ t, const int* __restrict__ rowptr,
        const int* __restrict__ col, const float* __restrict__ nrm,
        const float* __restrict__ dinv, const float* __restrict__ bias,
        float* __restrict__ out, int n, int relu) {
    int wid = __builtin_amdgcn_readfirstlane((int)blockIdx.x * 4 + ((int)threadIdx.x >> 6));
    int lane = threadIdx.x & 63;
    if (wid >= n) return;
    int beg = rowptr[wid], end = rowptr[wid + 1];
    float di = dinv[wid];
    const float2* tp = (const float2*)t;
    float2 sv = tp[(size_t)wid * 64 + lane];
    float w0 = di * di;
    float ax = sv.x * w0, ay = sv.y * w0;
    for (int e = beg; e < end; ++e) {
        int s = col[e];
        float w = nrm[e];
        float2 v = tp[(size_t)s * 64 + lane];
        ax = fmaf(v.x, w, ax);
        ay = fmaf(v.y, w, ay);
    }
    float2 b = ((const float2*)bias)[lane];
    ax += b.x; ay += b.y;
    if (relu) { ax = fmaxf(ax, 0.f); ay = fmaxf(ay, 0.f); }
    float2 o; o.x = ax; o.y = ay;
    ((float2*)out)[(size_t)wid * 64 + lane] = o;
}

// ---------------- launch ----------------

extern "C" void kernel_launch(void* const* d_in, const int* in_sizes, int n_in,
                              void* d_out, int out_size, void* d_ws, size_t ws_size,
                              hipStream_t stream) {
    const float* x  = (const float*)d_in[0];
    const int*   ei = (const int*)d_in[1];   // int64 in ref -> int32 on device
    const float* W1 = (const float*)d_in[2];
    const float* b1 = (const float*)d_in[3];
    const float* W2 = (const float*)d_in[4];
    const float* b2 = (const float*)d_in[5];
    const float* Wc = (const float*)d_in[6];
    const float* bc = (const float*)d_in[7];
    float*       out = (float*)d_out;

    const int n = N_NODES, e = N_EDGES;
    const int* srcp = ei;
    const int* dstp = ei + e;

    char* ws = (char*)d_ws;
    size_t off = 0;
    auto alloc = [&](size_t bytes) {
        void* p = ws + off;
        off += (bytes + 255) & ~(size_t)255;
        return p;
    };
    int*   cnt    = (int*)  alloc((size_t)n * 4);
    int*   scanT  = (int*)  alloc((size_t)n * 4);
    int*   bsum   = (int*)  alloc((size_t)NB_SCAN * 4);
    int*   boff   = (int*)  alloc((size_t)NB_SCAN * 4);
    int*   rowptr = (int*)  alloc((size_t)(n + 1) * 4);
    int*   fillc  = (int*)  alloc((size_t)n * 4);
    float* dinv   = (float*)alloc((size_t)n * 4);
    int*   col    = (int*)  alloc((size_t)e * 4);
    float* nrm    = (float*)alloc((size_t)e * 4);
    float* bufT   = (float*)alloc((size_t)n * 128 * 4);
    float* bufH   = (float*)alloc((size_t)n * 128 * 4);

    hipMemsetAsync(cnt,   0, (size_t)n * 4, stream);
    hipMemsetAsync(fillc, 0, (size_t)n * 4, stream);

    count_kernel<<<(e + 255) / 256, 256, 0, stream>>>(dstp, cnt, e);
    block_scan_kernel<<<NB_SCAN, 256, 0, stream>>>(cnt, scanT, bsum, dinv, n);
    bsum_scan_kernel<<<1, 256, 0, stream>>>(bsum, boff, NB_SCAN);
    rowptr_kernel<<<NB_SCAN, 256, 0, stream>>>(scanT, boff, rowptr, n);
    fill_kernel<<<(e + 255) / 256, 256, 0, stream>>>(srcp, dstp, rowptr, fillc,
                                                     dinv, col, nrm, e);

    const int gb = (n + 127) / 128;  // 391 blocks

    // conv1: t = x @ W1 ; h = relu(agg(t) + b1)
    gemm_kernel<128, 128, 8, 8><<<gb, 256, 0, stream>>>(x, W1, nullptr, bufT, n);
    agg_kernel<<<(n + 3) / 4, 256, 0, stream>>>(bufT, rowptr, col, nrm, dinv, b1, bufH, n, 1);
    // conv2
    gemm_kernel<128, 128, 8, 8><<<gb, 256, 0, stream>>>(bufH, W2, nullptr, bufT, n);
    agg_kernel<<<(n + 3) / 4, 256, 0, stream>>>(bufT, rowptr, col, nrm, dinv, b2, bufH, n, 1);
    // classifier: out = h @ Wc + bc
    gemm_kernel<64, 128, 4, 8><<<gb, 256, 0, stream>>>(bufH, Wc, bc, out, n);
}

// Round 5
// 291.252 us; speedup vs baseline: 1.7211x; 1.0483x over previous
//
#include <hip/hip_runtime.h>
#include <stdint.h>

#define N_NODES 50000
#define N_EDGES 800000
#define NB_SCAN ((N_NODES + 255) / 256)   // 196 blocks

// ---------------- CSR build ----------------

__global__ void count_kernel(const int* __restrict__ dst,
                             int* __restrict__ cnt, int e) {
    int i = blockIdx.x * blockDim.x + threadIdx.x;
    if (i < e) atomicAdd(&cnt[dst[i]], 1);
}

// phase 1: per-block inclusive scan of cnt + per-block totals; also dinv
__global__ __launch_bounds__(256) void block_scan_kernel(
        const int* __restrict__ cnt, int* __restrict__ scanT,
        int* __restrict__ bsum, float* __restrict__ dinv, int n) {
    __shared__ int sh[256];
    int t = threadIdx.x;
    int i = blockIdx.x * 256 + t;
    int v = (i < n) ? cnt[i] : 0;
    if (i < n) dinv[i] = rsqrtf((float)(v + 1));  // +1 self-loop
    sh[t] = v;
    __syncthreads();
    for (int off = 1; off < 256; off <<= 1) {
        int u = (t >= off) ? sh[t - off] : 0;
        __syncthreads();
        sh[t] += u;
        __syncthreads();
    }
    if (i < n) scanT[i] = sh[t];
    if (t == 255) bsum[blockIdx.x] = sh[255];
}

// phase 2: exclusive scan of block sums (nb <= 256)
__global__ __launch_bounds__(256) void bsum_scan_kernel(
        const int* __restrict__ bsum, int* __restrict__ boff, int nb) {
    __shared__ int sh[256];
    int t = threadIdx.x;
    sh[t] = (t < nb) ? bsum[t] : 0;
    __syncthreads();
    for (int off = 1; off < 256; off <<= 1) {
        int u = (t >= off) ? sh[t - off] : 0;
        __syncthreads();
        sh[t] += u;
        __syncthreads();
    }
    if (t < nb) boff[t] = (t == 0) ? 0 : sh[t - 1];
}

// phase 3: rowptr[i+1] = scanT[i] + boff[block]; rowptr[0] = 0
__global__ __launch_bounds__(256) void rowptr_kernel(
        const int* __restrict__ scanT, const int* __restrict__ boff,
        int* __restrict__ rowptr, int n) {
    int i = blockIdx.x * 256 + threadIdx.x;
    if (i < n) {
        rowptr[i + 1] = scanT[i] + boff[blockIdx.x];
        if (i == 0) rowptr[0] = 0;
    }
}

__global__ void fill_kernel(const int* __restrict__ src,
                            const int* __restrict__ dst,
                            const int* __restrict__ rowptr,
                            int* __restrict__ fill,
                            const float* __restrict__ dinv,
                            int* __restrict__ col, float* __restrict__ nrm, int e) {
    int i = blockIdx.x * blockDim.x + threadIdx.x;
    if (i >= e) return;
    int s = src[i], d = dst[i];
    int pos = rowptr[d] + atomicAdd(&fill[d], 1);
    col[pos] = s;
    nrm[pos] = dinv[s] * dinv[d];
}

// ---------------- tiled GEMM: out[n,C] = A[n,128] @ W[128,C] (+bias) ----------------
// BM=64 -> 782 blocks (~3/CU) for latency hiding.

template <int C, int BM, int RT, int CT>
__global__ __launch_bounds__(256, 4) void gemm_kernel(
        const float* __restrict__ A, const float* __restrict__ W,
        const float* __restrict__ bias, float* __restrict__ out, int n) {
    constexpr int KC = 32;
    constexpr int NCOLT = C / CT;
    constexpr int NROWT = BM / RT;
    static_assert(NCOLT * NROWT == 256, "bad tile");
    constexpr int PAD = BM + 4;
    constexpr int K4 = KC / 4;
    constexpr int XLOADS = (BM * K4) / 256;
    constexpr int WLOADS = (KC * C) / 1024;
    constexpr int NT = 128 / KC;

    __shared__ float xT[KC * PAD];
    __shared__ float Wl[KC * C];

    const int tid = threadIdx.x;
    const int colt = tid % NCOLT;
    const int rowt = tid / NCOLT;
    const int row0 = blockIdx.x * BM;

    float acc[RT][CT];
#pragma unroll
    for (int r = 0; r < RT; ++r)
#pragma unroll
        for (int c = 0; c < CT; ++c) acc[r][c] = 0.f;

    int xk4[XLOADS], xrow[XLOADS];
    const float* aptr[XLOADS];
#pragma unroll
    for (int i = 0; i < XLOADS; ++i) {
        int flat = tid + i * 256;
        xk4[i] = flat % K4;
        xrow[i] = flat / K4;
        int rg = row0 + xrow[i];
        if (rg > n - 1) rg = n - 1;
        aptr[i] = A + (size_t)rg * 128 + xk4[i] * 4;
    }
    float4 xr[XLOADS];
#pragma unroll
    for (int i = 0; i < XLOADS; ++i) xr[i] = *(const float4*)aptr[i];

    for (int t = 0; t < NT; ++t) {
#pragma unroll
        for (int i = 0; i < WLOADS; ++i) {
            int f4 = tid + i * 256;
            *(float4*)&Wl[f4 * 4] = *(const float4*)&W[t * KC * C + f4 * 4];
        }
#pragma unroll
        for (int i = 0; i < XLOADS; ++i) {
            xT[(xk4[i] * 4 + 0) * PAD + xrow[i]] = xr[i].x;
            xT[(xk4[i] * 4 + 1) * PAD + xrow[i]] = xr[i].y;
            xT[(xk4[i] * 4 + 2) * PAD + xrow[i]] = xr[i].z;
            xT[(xk4[i] * 4 + 3) * PAD + xrow[i]] = xr[i].w;
        }
        if (t < NT - 1) {
#pragma unroll
            for (int i = 0; i < XLOADS; ++i)
                xr[i] = *(const float4*)(aptr[i] + (t + 1) * KC);
        }
        __syncthreads();

#pragma unroll 2
        for (int kk = 0; kk < KC; ++kk) {
            float xv[RT], wv[CT];
            {
                const float* xb = &xT[kk * PAD + rowt * RT];
                float4 a = *(const float4*)xb;
                xv[0] = a.x; xv[1] = a.y; xv[2] = a.z; xv[3] = a.w;
                if constexpr (RT == 8) {
                    float4 b = *(const float4*)(xb + 4);
                    xv[4] = b.x; xv[5] = b.y; xv[6] = b.z; xv[7] = b.w;
                }
            }
            {
                const float* wb = &Wl[kk * C + colt * CT];
                float4 a = *(const float4*)wb;
                wv[0] = a.x; wv[1] = a.y; wv[2] = a.z; wv[3] = a.w;
                if constexpr (CT == 8) {
                    float4 b = *(const float4*)(wb + 4);
                    wv[4] = b.x; wv[5] = b.y; wv[6] = b.z; wv[7] = b.w;
                }
            }
#pragma unroll
            for (int r = 0; r < RT; ++r)
#pragma unroll
                for (int c = 0; c < CT; ++c)
                    acc[r][c] = fmaf(xv[r], wv[c], acc[r][c]);
        }
        __syncthreads();
    }

    float bv[CT];
#pragma unroll
    for (int c = 0; c < CT; ++c) bv[c] = bias ? bias[colt * CT + c] : 0.f;
#pragma unroll
    for (int r = 0; r < RT; ++r) {
        int rg = row0 + rowt * RT + r;
        if (rg < n) {
            float* op = &out[(size_t)rg * C + colt * CT];
            float4 o0;
            o0.x = acc[r][0] + bv[0]; o0.y = acc[r][1] + bv[1];
            o0.z = acc[r][2] + bv[2]; o0.w = acc[r][3] + bv[3];
            *(float4*)op = o0;
            if constexpr (CT == 8) {
                float4 o1;
                o1.x = acc[r][4] + bv[4]; o1.y = acc[r][5] + bv[5];
                o1.z = acc[r][6] + bv[6]; o1.w = acc[r][7] + bv[7];
                *(float4*)(op + 4) = o1;
            }
        }
    }
}

// ---------------- aggregation: unrolled x4, 4 accumulator pairs for MLP ----------------

__global__ __launch_bounds__(256) void agg_kernel(
        const float* __restrict__ t, const int* __restrict__ rowptr,
        const int* __restrict__ col, const float* __restrict__ nrm,
        const float* __restrict__ dinv, const float* __restrict__ bias,
        float* __restrict__ out, int n, int relu) {
    int wid = __builtin_amdgcn_readfirstlane((int)blockIdx.x * 4 + ((int)threadIdx.x >> 6));
    int lane = threadIdx.x & 63;
    if (wid >= n) return;
    int beg = rowptr[wid], end = rowptr[wid + 1];
    float di = dinv[wid];
    const float2* tp = (const float2*)t;
    float2 sv = tp[(size_t)wid * 64 + lane];
    float w0 = di * di;
    float ax0 = sv.x * w0, ay0 = sv.y * w0;
    float ax1 = 0.f, ay1 = 0.f, ax2 = 0.f, ay2 = 0.f, ax3 = 0.f, ay3 = 0.f;

    int e = beg;
    for (; e + 4 <= end; e += 4) {
        int s0 = col[e], s1 = col[e + 1], s2 = col[e + 2], s3 = col[e + 3];
        float w0_ = nrm[e], w1_ = nrm[e + 1], w2_ = nrm[e + 2], w3_ = nrm[e + 3];
        float2 v0 = tp[(size_t)s0 * 64 + lane];
        float2 v1 = tp[(size_t)s1 * 64 + lane];
        float2 v2 = tp[(size_t)s2 * 64 + lane];
        float2 v3 = tp[(size_t)s3 * 64 + lane];
        ax0 = fmaf(v0.x, w0_, ax0); ay0 = fmaf(v0.y, w0_, ay0);
        ax1 = fmaf(v1.x, w1_, ax1); ay1 = fmaf(v1.y, w1_, ay1);
        ax2 = fmaf(v2.x, w2_, ax2); ay2 = fmaf(v2.y, w2_, ay2);
        ax3 = fmaf(v3.x, w3_, ax3); ay3 = fmaf(v3.y, w3_, ay3);
    }
    for (; e < end; ++e) {
        int s = col[e];
        float w = nrm[e];
        float2 v = tp[(size_t)s * 64 + lane];
        ax0 = fmaf(v.x, w, ax0); ay0 = fmaf(v.y, w, ay0);
    }
    float ax = (ax0 + ax1) + (ax2 + ax3);
    float ay = (ay0 + ay1) + (ay2 + ay3);

    float2 b = ((const float2*)bias)[lane];
    ax += b.x; ay += b.y;
    if (relu) { ax = fmaxf(ax, 0.f); ay = fmaxf(ay, 0.f); }
    float2 o; o.x = ax; o.y = ay;
    ((float2*)out)[(size_t)wid * 64 + lane] = o;
}

// ---------------- launch ----------------

extern "C" void kernel_launch(void* const* d_in, const int* in_sizes, int n_in,
                              void* d_out, int out_size, void* d_ws, size_t ws_size,
                              hipStream_t stream) {
    const float* x  = (const float*)d_in[0];
    const int*   ei = (const int*)d_in[1];   // int64 in ref -> int32 on device
    const float* W1 = (const float*)d_in[2];
    const float* b1 = (const float*)d_in[3];
    const float* W2 = (const float*)d_in[4];
    const float* b2 = (const float*)d_in[5];
    const float* Wc = (const float*)d_in[6];
    const float* bc = (const float*)d_in[7];
    float*       out = (float*)d_out;

    const int n = N_NODES, e = N_EDGES;
    const int* srcp = ei;
    const int* dstp = ei + e;

    char* ws = (char*)d_ws;
    size_t off = 0;
    auto alloc = [&](size_t bytes) {
        void* p = ws + off;
        off += (bytes + 255) & ~(size_t)255;
        return p;
    };
    int*   cnt    = (int*)  alloc((size_t)n * 4);
    int*   scanT  = (int*)  alloc((size_t)n * 4);
    int*   bsum   = (int*)  alloc((size_t)NB_SCAN * 4);
    int*   boff   = (int*)  alloc((size_t)NB_SCAN * 4);
    int*   rowptr = (int*)  alloc((size_t)(n + 1) * 4);
    int*   fillc  = (int*)  alloc((size_t)n * 4);
    float* dinv   = (float*)alloc((size_t)n * 4);
    int*   col    = (int*)  alloc((size_t)e * 4);
    float* nrm    = (float*)alloc((size_t)e * 4);
    float* bufT   = (float*)alloc((size_t)n * 128 * 4);
    float* bufH   = (float*)alloc((size_t)n * 128 * 4);

    hipMemsetAsync(cnt,   0, (size_t)n * 4, stream);
    hipMemsetAsync(fillc, 0, (size_t)n * 4, stream);

    count_kernel<<<(e + 255) / 256, 256, 0, stream>>>(dstp, cnt, e);
    block_scan_kernel<<<NB_SCAN, 256, 0, stream>>>(cnt, scanT, bsum, dinv, n);
    bsum_scan_kernel<<<1, 256, 0, stream>>>(bsum, boff, NB_SCAN);
    rowptr_kernel<<<NB_SCAN, 256, 0, stream>>>(scanT, boff, rowptr, n);
    fill_kernel<<<(e + 255) / 256, 256, 0, stream>>>(srcp, dstp, rowptr, fillc,
                                                     dinv, col, nrm, e);

    const int gb = (n + 63) / 64;  // 782 blocks, ~3/CU

    // conv1: t = x @ W1 ; h = relu(agg(t) + b1)
    gemm_kernel<128, 64, 4, 8><<<gb, 256, 0, stream>>>(x, W1, nullptr, bufT, n);
    agg_kernel<<<(n + 3) / 4, 256, 0, stream>>>(bufT, rowptr, col, nrm, dinv, b1, bufH, n, 1);
    // conv2
    gemm_kernel<128, 64, 4, 8><<<gb, 256, 0, stream>>>(bufH, W2, nullptr, bufT, n);
    agg_kernel<<<(n + 3) / 4, 256, 0, stream>>>(bufT, rowptr, col, nrm, dinv, b2, bufH, n, 1);
    // classifier: out = h @ Wc + bc
    gemm_kernel<64, 64, 4, 4><<<gb, 256, 0, stream>>>(bufH, Wc, bc, out, n);
}

// Round 6
// 241.201 us; speedup vs baseline: 2.0783x; 1.2075x over previous
//
#include <hip/hip_runtime.h>
#include <hip/hip_fp16.h>
#include <stdint.h>

#define N_NODES 50000
#define N_EDGES 800000
#define NB_SCAN ((N_NODES + 255) / 256)   // 196 blocks

// ---------------- CSR build ----------------

__global__ void count_kernel(const int* __restrict__ dst,
                             int* __restrict__ cnt, int e) {
    int i = blockIdx.x * blockDim.x + threadIdx.x;
    if (i < e) atomicAdd(&cnt[dst[i]], 1);
}

__global__ __launch_bounds__(256) void block_scan_kernel(
        const int* __restrict__ cnt, int* __restrict__ scanT,
        int* __restrict__ bsum, float* __restrict__ dinv, int n) {
    __shared__ int sh[256];
    int t = threadIdx.x;
    int i = blockIdx.x * 256 + t;
    int v = (i < n) ? cnt[i] : 0;
    if (i < n) dinv[i] = rsqrtf((float)(v + 1));  // +1 self-loop
    sh[t] = v;
    __syncthreads();
    for (int off = 1; off < 256; off <<= 1) {
        int u = (t >= off) ? sh[t - off] : 0;
        __syncthreads();
        sh[t] += u;
        __syncthreads();
    }
    if (i < n) scanT[i] = sh[t];
    if (t == 255) bsum[blockIdx.x] = sh[255];
}

__global__ __launch_bounds__(256) void bsum_scan_kernel(
        const int* __restrict__ bsum, int* __restrict__ boff, int nb) {
    __shared__ int sh[256];
    int t = threadIdx.x;
    sh[t] = (t < nb) ? bsum[t] : 0;
    __syncthreads();
    for (int off = 1; off < 256; off <<= 1) {
        int u = (t >= off) ? sh[t - off] : 0;
        __syncthreads();
        sh[t] += u;
        __syncthreads();
    }
    if (t < nb) boff[t] = (t == 0) ? 0 : sh[t - 1];
}

__global__ __launch_bounds__(256) void rowptr_kernel(
        const int* __restrict__ scanT, const int* __restrict__ boff,
        int* __restrict__ rowptr, int n) {
    int i = blockIdx.x * 256 + threadIdx.x;
    if (i < n) {
        rowptr[i + 1] = scanT[i] + boff[blockIdx.x];
        if (i == 0) rowptr[0] = 0;
    }
}

__global__ void fill_kernel(const int* __restrict__ src,
                            const int* __restrict__ dst,
                            const int* __restrict__ rowptr,
                            int* __restrict__ fill,
                            const float* __restrict__ dinv,
                            int* __restrict__ col, float* __restrict__ nrm, int e) {
    int i = blockIdx.x * blockDim.x + threadIdx.x;
    if (i >= e) return;
    int s = src[i], d = dst[i];
    int pos = rowptr[d] + atomicAdd(&fill[d], 1);
    col[pos] = s;
    nrm[pos] = dinv[s] * dinv[d];
}

// ---------------- tiled GEMM: out[n,C] = A[n,128] @ W[128,C] (+bias) ----------------
// OutT = float (fp32 out) or __half (fp16 message buffer).

static __device__ __forceinline__ unsigned pack_h2(float a, float b) {
    __half2 h = __floats2half2_rn(a, b);
    return *reinterpret_cast<unsigned*>(&h);
}

template <int C, int BM, int RT, int CT, typename OutT>
__global__ __launch_bounds__(256, 4) void gemm_kernel(
        const float* __restrict__ A, const float* __restrict__ W,
        const float* __restrict__ bias, OutT* __restrict__ out, int n) {
    constexpr int KC = 32;
    constexpr int NCOLT = C / CT;
    constexpr int NROWT = BM / RT;
    static_assert(NCOLT * NROWT == 256, "bad tile");
    constexpr int PAD = BM + 4;
    constexpr int K4 = KC / 4;
    constexpr int XLOADS = (BM * K4) / 256;
    constexpr int WLOADS = (KC * C) / 1024;
    constexpr int NT = 128 / KC;

    __shared__ float xT[KC * PAD];
    __shared__ float Wl[KC * C];

    const int tid = threadIdx.x;
    const int colt = tid % NCOLT;
    const int rowt = tid / NCOLT;
    const int row0 = blockIdx.x * BM;

    float acc[RT][CT];
#pragma unroll
    for (int r = 0; r < RT; ++r)
#pragma unroll
        for (int c = 0; c < CT; ++c) acc[r][c] = 0.f;

    int xk4[XLOADS], xrow[XLOADS];
    const float* aptr[XLOADS];
#pragma unroll
    for (int i = 0; i < XLOADS; ++i) {
        int flat = tid + i * 256;
        xk4[i] = flat % K4;
        xrow[i] = flat / K4;
        int rg = row0 + xrow[i];
        if (rg > n - 1) rg = n - 1;
        aptr[i] = A + (size_t)rg * 128 + xk4[i] * 4;
    }
    float4 xr[XLOADS];
#pragma unroll
    for (int i = 0; i < XLOADS; ++i) xr[i] = *(const float4*)aptr[i];

    for (int t = 0; t < NT; ++t) {
#pragma unroll
        for (int i = 0; i < WLOADS; ++i) {
            int f4 = tid + i * 256;
            *(float4*)&Wl[f4 * 4] = *(const float4*)&W[t * KC * C + f4 * 4];
        }
#pragma unroll
        for (int i = 0; i < XLOADS; ++i) {
            xT[(xk4[i] * 4 + 0) * PAD + xrow[i]] = xr[i].x;
            xT[(xk4[i] * 4 + 1) * PAD + xrow[i]] = xr[i].y;
            xT[(xk4[i] * 4 + 2) * PAD + xrow[i]] = xr[i].z;
            xT[(xk4[i] * 4 + 3) * PAD + xrow[i]] = xr[i].w;
        }
        if (t < NT - 1) {
#pragma unroll
            for (int i = 0; i < XLOADS; ++i)
                xr[i] = *(const float4*)(aptr[i] + (t + 1) * KC);
        }
        __syncthreads();

#pragma unroll 2
        for (int kk = 0; kk < KC; ++kk) {
            float xv[RT], wv[CT];
            {
                const float* xb = &xT[kk * PAD + rowt * RT];
                float4 a = *(const float4*)xb;
                xv[0] = a.x; xv[1] = a.y; xv[2] = a.z; xv[3] = a.w;
                if constexpr (RT == 8) {
                    float4 b = *(const float4*)(xb + 4);
                    xv[4] = b.x; xv[5] = b.y; xv[6] = b.z; xv[7] = b.w;
                }
            }
            {
                const float* wb = &Wl[kk * C + colt * CT];
                float4 a = *(const float4*)wb;
                wv[0] = a.x; wv[1] = a.y; wv[2] = a.z; wv[3] = a.w;
                if constexpr (CT == 8) {
                    float4 b = *(const float4*)(wb + 4);
                    wv[4] = b.x; wv[5] = b.y; wv[6] = b.z; wv[7] = b.w;
                }
            }
#pragma unroll
            for (int r = 0; r < RT; ++r)
#pragma unroll
                for (int c = 0; c < CT; ++c)
                    acc[r][c] = fmaf(xv[r], wv[c], acc[r][c]);
        }
        __syncthreads();
    }

    float bv[CT];
#pragma unroll
    for (int c = 0; c < CT; ++c) bv[c] = bias ? bias[colt * CT + c] : 0.f;
#pragma unroll
    for (int r = 0; r < RT; ++r) {
        int rg = row0 + rowt * RT + r;
        if (rg < n) {
            OutT* op = &out[(size_t)rg * C + colt * CT];
            if constexpr (__hip_internal::is_same<OutT, __half>::value) {
                static_assert(CT == 8, "fp16 path assumes CT==8");
                uint4 u;
                u.x = pack_h2(acc[r][0] + bv[0], acc[r][1] + bv[1]);
                u.y = pack_h2(acc[r][2] + bv[2], acc[r][3] + bv[3]);
                u.z = pack_h2(acc[r][4] + bv[4], acc[r][5] + bv[5]);
                u.w = pack_h2(acc[r][6] + bv[6], acc[r][7] + bv[7]);
                *(uint4*)op = u;   // 8 halves = 16 B, 16-B aligned
            } else {
                float4 o0;
                o0.x = acc[r][0] + bv[0]; o0.y = acc[r][1] + bv[1];
                o0.z = acc[r][2] + bv[2]; o0.w = acc[r][3] + bv[3];
                *(float4*)op = o0;
                if constexpr (CT == 8) {
                    float4 o1;
                    o1.x = acc[r][4] + bv[4]; o1.y = acc[r][5] + bv[5];
                    o1.z = acc[r][6] + bv[6]; o1.w = acc[r][7] + bv[7];
                    *(float4*)(op + 4) = o1;
                }
            }
        }
    }
}

// ---------------- aggregation: fp16 messages, fp32 accumulate, 8 gathers in flight ----------------

__global__ __launch_bounds__(256) void agg_kernel(
        const __half2* __restrict__ t, const int* __restrict__ rowptr,
        const int* __restrict__ col, const float* __restrict__ nrm,
        const float* __restrict__ dinv, const float* __restrict__ bias,
        float* __restrict__ out, int n, int relu) {
    int wid = __builtin_amdgcn_readfirstlane((int)blockIdx.x * 4 + ((int)threadIdx.x >> 6));
    int lane = threadIdx.x & 63;
    if (wid >= n) return;
    int beg = rowptr[wid], end = rowptr[wid + 1];
    float di = dinv[wid];
    float2 sv = __half22float2(t[(size_t)wid * 64 + lane]);
    float w0 = di * di;
    float ax0 = sv.x * w0, ay0 = sv.y * w0;
    float ax1 = 0.f, ay1 = 0.f, ax2 = 0.f, ay2 = 0.f, ax3 = 0.f, ay3 = 0.f;

    int e = beg;
    for (; e + 8 <= end; e += 8) {
        int s0 = col[e],     s1 = col[e + 1], s2 = col[e + 2], s3 = col[e + 3];
        int s4 = col[e + 4], s5 = col[e + 5], s6 = col[e + 6], s7 = col[e + 7];
        float n0 = nrm[e],     n1 = nrm[e + 1], n2 = nrm[e + 2], n3 = nrm[e + 3];
        float n4 = nrm[e + 4], n5 = nrm[e + 5], n6 = nrm[e + 6], n7 = nrm[e + 7];
        __half2 h0 = t[(size_t)s0 * 64 + lane];
        __half2 h1 = t[(size_t)s1 * 64 + lane];
        __half2 h2 = t[(size_t)s2 * 64 + lane];
        __half2 h3 = t[(size_t)s3 * 64 + lane];
        __half2 h4 = t[(size_t)s4 * 64 + lane];
        __half2 h5 = t[(size_t)s5 * 64 + lane];
        __half2 h6 = t[(size_t)s6 * 64 + lane];
        __half2 h7 = t[(size_t)s7 * 64 + lane];
        float2 v;
        v = __half22float2(h0); ax0 = fmaf(v.x, n0, ax0); ay0 = fmaf(v.y, n0, ay0);
        v = __half22float2(h1); ax1 = fmaf(v.x, n1, ax1); ay1 = fmaf(v.y, n1, ay1);
        v = __half22float2(h2); ax2 = fmaf(v.x, n2, ax2); ay2 = fmaf(v.y, n2, ay2);
        v = __half22float2(h3); ax3 = fmaf(v.x, n3, ax3); ay3 = fmaf(v.y, n3, ay3);
        v = __half22float2(h4); ax0 = fmaf(v.x, n4, ax0); ay0 = fmaf(v.y, n4, ay0);
        v = __half22float2(h5); ax1 = fmaf(v.x, n5, ax1); ay1 = fmaf(v.y, n5, ay1);
        v = __half22float2(h6); ax2 = fmaf(v.x, n6, ax2); ay2 = fmaf(v.y, n6, ay2);
        v = __half22float2(h7); ax3 = fmaf(v.x, n7, ax3); ay3 = fmaf(v.y, n7, ay3);
    }
    for (; e < end; ++e) {
        int s = col[e];
        float w = nrm[e];
        float2 v = __half22float2(t[(size_t)s * 64 + lane]);
        ax0 = fmaf(v.x, w, ax0); ay0 = fmaf(v.y, w, ay0);
    }
    float ax = (ax0 + ax1) + (ax2 + ax3);
    float ay = (ay0 + ay1) + (ay2 + ay3);

    float2 b = ((const float2*)bias)[lane];
    ax += b.x; ay += b.y;
    if (relu) { ax = fmaxf(ax, 0.f); ay = fmaxf(ay, 0.f); }
    float2 o; o.x = ax; o.y = ay;
    ((float2*)out)[(size_t)wid * 64 + lane] = o;
}

// ---------------- launch ----------------

extern "C" void kernel_launch(void* const* d_in, const int* in_sizes, int n_in,
                              void* d_out, int out_size, void* d_ws, size_t ws_size,
                              hipStream_t stream) {
    const float* x  = (const float*)d_in[0];
    const int*   ei = (const int*)d_in[1];   // int64 in ref -> int32 on device
    const float* W1 = (const float*)d_in[2];
    const float* b1 = (const float*)d_in[3];
    const float* W2 = (const float*)d_in[4];
    const float* b2 = (const float*)d_in[5];
    const float* Wc = (const float*)d_in[6];
    const float* bc = (const float*)d_in[7];
    float*       out = (float*)d_out;

    const int n = N_NODES, e = N_EDGES;
    const int* srcp = ei;
    const int* dstp = ei + e;

    char* ws = (char*)d_ws;
    size_t off = 0;
    auto alloc = [&](size_t bytes) {
        void* p = ws + off;
        off += (bytes + 255) & ~(size_t)255;
        return p;
    };
    int*    cnt    = (int*)   alloc((size_t)n * 4);
    int*    scanT  = (int*)   alloc((size_t)n * 4);
    int*    bsum   = (int*)   alloc((size_t)NB_SCAN * 4);
    int*    boff   = (int*)   alloc((size_t)NB_SCAN * 4);
    int*    rowptr = (int*)   alloc((size_t)(n + 1) * 4);
    int*    fillc  = (int*)   alloc((size_t)n * 4);
    float*  dinv   = (float*) alloc((size_t)n * 4);
    int*    col    = (int*)   alloc((size_t)e * 4);
    float*  nrm    = (float*) alloc((size_t)e * 4);
    __half* bufT   = (__half*)alloc((size_t)n * 128 * 2);   // fp16 messages
    float*  bufH   = (float*) alloc((size_t)n * 128 * 4);

    hipMemsetAsync(cnt,   0, (size_t)n * 4, stream);
    hipMemsetAsync(fillc, 0, (size_t)n * 4, stream);

    count_kernel<<<(e + 255) / 256, 256, 0, stream>>>(dstp, cnt, e);
    block_scan_kernel<<<NB_SCAN, 256, 0, stream>>>(cnt, scanT, bsum, dinv, n);
    bsum_scan_kernel<<<1, 256, 0, stream>>>(bsum, boff, NB_SCAN);
    rowptr_kernel<<<NB_SCAN, 256, 0, stream>>>(scanT, boff, rowptr, n);
    fill_kernel<<<(e + 255) / 256, 256, 0, stream>>>(srcp, dstp, rowptr, fillc,
                                                     dinv, col, nrm, e);

    const int gb = (n + 63) / 64;  // 782 blocks, ~3/CU

    // conv1: t = x @ W1 (fp16) ; h = relu(agg(t) + b1) (fp32)
    gemm_kernel<128, 64, 4, 8, __half><<<gb, 256, 0, stream>>>(x, W1, nullptr, bufT, n);
    agg_kernel<<<(n + 3) / 4, 256, 0, stream>>>((const __half2*)bufT, rowptr, col, nrm,
                                                dinv, b1, bufH, n, 1);
    // conv2
    gemm_kernel<128, 64, 4, 8, __half><<<gb, 256, 0, stream>>>(bufH, W2, nullptr, bufT, n);
    agg_kernel<<<(n + 3) / 4, 256, 0, stream>>>((const __half2*)bufT, rowptr, col, nrm,
                                                dinv, b2, bufH, n, 1);
    // classifier: out = h @ Wc + bc (fp32)
    gemm_kernel<64, 64, 4, 4, float><<<gb, 256, 0, stream>>>(bufH, Wc, bc, out, n);
}